// Round 4
// baseline (121.440 us; speedup 1.0000x reference)
//
#include <hip/hip_runtime.h>

// CASSI forward A^T(A(x)) — R3: float2 register gather (R2 structure) +
// LDS y2 exchange + float4 aligned output stores.
//
// out[b,l,m,n] = phi[l,m,n] * y2[b,m,n+2l]
// y2[b,m,c]    = sum_l phi[l,m,c-2l] * x[b,l,m,c-2l]   (valid 0<=c-2l<N)
//
// R2 post-mortem: HBM traffic is write-dominated (WRITE 253MB > FETCH 118MB)
// and 8B nontemporal stores added ~10% write over-traffic. Fix: keep the
// proven float2 gather (phase 1), park y2 in LDS (1.4KB/row, swizzled), then
// re-tile to (band, n-quad) ownership so every output store is an aligned
// 16B float4 full-line write. phi re-read in phase 2 is L2/L3-resident
// (7MB total, all 32 batches share it) -> no extra HBM fetch.

constexpr int L_BANDS = 28;
constexpr int M_DIM   = 256;
constexpr int N_DIM   = 256;
constexpr int SHIFT   = 2;
constexpr int N_OUT   = N_DIM + SHIFT * (L_BANDS - 1);  // 310
constexpr int NPAIR   = N_OUT / 2;                      // 155
constexpr int MN      = M_DIM * N_DIM;                  // 65536
constexpr int Y2PAD   = 352;                            // swz(309)=347 max
constexpr int P2UNITS = 2 * L_BANDS * (N_DIM / 4);      // 3584 float4 units

typedef float v2f __attribute__((ext_vector_type(2)));
typedef float v4f __attribute__((ext_vector_type(4)));

// bank-deconflict swizzle for y2: phase-2 reads have word-stride 4 across
// lanes (8-way conflict on 32 banks); +w/8 skew spreads them.
__device__ __forceinline__ int swz(int w) { return w + (w >> 3); }

__global__ __launch_bounds__(320) void cassi_fwd_kernel(
    const float* __restrict__ x,
    const float* __restrict__ phi,
    float* __restrict__ out)
{
    __shared__ float y2s[2][Y2PAD];

    const int t  = threadIdx.x;
    const int r  = (t >= 160) ? 1 : 0;   // which of the block's two m-rows
    const int p  = t - 160 * r;          // column-pair index within the row
    const int b  = blockIdx.x >> 7;      // / (M_DIM/2)
    const int m0 = (blockIdx.x & 127) << 1;

    // ---- Phase 1: register float2 gather -> y2 (identical math to R2) ----
    if (p < NPAIR) {
        const int m  = m0 + r;
        const int c0 = p << 1;           // even dispersed column
        const float* xb = x   + b * (L_BANDS * MN) + m * N_DIM;
        const float* pb = phi +                      m * N_DIM;

        v2f xr[L_BANDS];
        v2f pr[L_BANDS];
        #pragma unroll
        for (int l = 0; l < L_BANDS; ++l) {
            const int n0 = c0 - SHIFT * l;          // even
            const bool v = (unsigned)n0 < (unsigned)(N_DIM - 1);
            if (v) {
                xr[l] = *(const v2f*)(xb + l * MN + n0);
                pr[l] = *(const v2f*)(pb + l * MN + n0);
            } else {
                xr[l] = (v2f)(0.0f);
                pr[l] = (v2f)(0.0f);
            }
        }
        v2f acc = (v2f)(0.0f);
        #pragma unroll
        for (int l = 0; l < L_BANDS; ++l) {
            acc += xr[l] * pr[l];
        }
        y2s[r][swz(c0)]     = acc.x;
        y2s[r][swz(c0 + 1)] = acc.y;
    }
    __syncthreads();

    // ---- Phase 2: (row, band, n-quad) ownership; aligned float4 stores ----
    float* ob = out + b * (L_BANDS * MN);
    for (int u = t; u < P2UNITS; u += 320) {
        const int rr = u / (L_BANDS * 64);      // 0 or 1
        const int v  = u - rr * (L_BANDS * 64);
        const int l  = v >> 6;                  // band
        const int q  = v & 63;                  // n-quad
        const int n0 = q << 2;
        const int m  = m0 + rr;
        const int w  = n0 + SHIFT * l;          // dispersed col of n0

        const v4f p4 = *(const v4f*)(phi + l * MN + m * N_DIM + n0);
        v4f y4;
        y4.x = y2s[rr][swz(w)];
        y4.y = y2s[rr][swz(w + 1)];
        y4.z = y2s[rr][swz(w + 2)];
        y4.w = y2s[rr][swz(w + 3)];
        *(v4f*)(ob + l * MN + m * N_DIM + n0) = p4 * y4;
    }
}

extern "C" void kernel_launch(void* const* d_in, const int* in_sizes, int n_in,
                              void* d_out, int out_size, void* d_ws, size_t ws_size,
                              hipStream_t stream) {
    const float* x   = (const float*)d_in[0];
    const float* phi = (const float*)d_in[1];
    float*       out = (float*)d_out;

    const int B = in_sizes[0] / (L_BANDS * MN);   // 32

    dim3 grid(B * (M_DIM / 2));  // one block per (b, m-pair): 4096 blocks
    dim3 block(320);             // 2 rows x 155 active pair-threads
    cassi_fwd_kernel<<<grid, block, 0, stream>>>(x, phi, out);
}

// Round 5
// 109.025 us; speedup vs baseline: 1.1139x; 1.1139x over previous
//
#include <hip/hip_runtime.h>

// CASSI forward A^T(A(x)) — R4: R2's register-resident float2 structure,
// with PLAIN stores (nontemporal hint removed).
//
// out[b,l,m,n] = phi[l,m,n] * y2[b,m,n+2l]
// y2[b,m,c]    = sum_l phi[l,m,c-2l] * x[b,l,m,c-2l]   (valid 0<=c-2l<N)
//
// History:
//  R1 scalar, plain stores:  WRITE 229 MB (ideal), 100 µs (latency-bound).
//  R2 float2, nt stores:     WRITE 253 MB (+10% — nt bypasses L2 write
//                            combining), 81 µs.
//  R3 LDS + float4 stores:   WRITE ideal but VGPR 88->64 broke the
//                            all-loads-in-flight property + LDS conflicts;
//                            121 µs. Reverted.
//  R4 = R2 minus the nt hint: keep all 56 8B loads in flight per thread
//       (VGPR ~88), let L2 write-combine the contiguous float2 stores.

constexpr int L_BANDS = 28;
constexpr int M_DIM   = 256;
constexpr int N_DIM   = 256;
constexpr int SHIFT   = 2;
constexpr int N_OUT   = N_DIM + SHIFT * (L_BANDS - 1);  // 310
constexpr int NPAIR   = N_OUT / 2;                      // 155 column-pairs
constexpr int MN      = M_DIM * N_DIM;                  // 65536

typedef float v2f __attribute__((ext_vector_type(2)));

__global__ __launch_bounds__(320) void cassi_fwd_kernel(
    const float* __restrict__ x,
    const float* __restrict__ phi,
    float* __restrict__ out)
{
    const int t = threadIdx.x;
    const int r = (t >= 160) ? 1 : 0;   // which of the block's two m-rows
    const int p = t - 160 * r;          // pair index within the row
    if (p >= NPAIR) return;             // 5 idle lanes per half (no barriers)

    const int b  = blockIdx.x >> 7;                 // / (M_DIM/2)
    const int m  = ((blockIdx.x & 127) << 1) + r;   // 2*(blk%128) + r
    const int c0 = p << 1;                          // even dispersed column

    const float* xb = x   + b * (L_BANDS * MN) + m * N_DIM;  // x[b, 0, m, 0]
    const float* pb = phi +                      m * N_DIM;  // phi[0, m, 0]
    float*       ob = out + b * (L_BANDS * MN) + m * N_DIM;  // out[b, 0, m, 0]

    v2f xr[L_BANDS];
    v2f pr[L_BANDS];

    // Phase 1a: issue ALL loads (56 x 8B per thread) before any consumption.
    #pragma unroll
    for (int l = 0; l < L_BANDS; ++l) {
        const int n0 = c0 - SHIFT * l;                  // even
        const bool v = (unsigned)n0 < (unsigned)(N_DIM - 1);
        if (v) {
            xr[l] = *(const v2f*)(xb + l * MN + n0);
            pr[l] = *(const v2f*)(pb + l * MN + n0);
        } else {
            xr[l] = (v2f)(0.0f);
            pr[l] = (v2f)(0.0f);
        }
    }

    // Phase 1b: reduce to y2[b,m,c0] / y2[b,m,c0+1].
    v2f acc = (v2f)(0.0f);
    #pragma unroll
    for (int l = 0; l < L_BANDS; ++l) {
        acc += xr[l] * pr[l];
    }

    // Phase 2: scatter y2 to every output element that consumes it.
    #pragma unroll
    for (int l = 0; l < L_BANDS; ++l) {
        const int n0 = c0 - SHIFT * l;
        if ((unsigned)n0 < (unsigned)(N_DIM - 1)) {
            *(v2f*)(ob + l * MN + n0) = pr[l] * acc;
        }
    }
}

extern "C" void kernel_launch(void* const* d_in, const int* in_sizes, int n_in,
                              void* d_out, int out_size, void* d_ws, size_t ws_size,
                              hipStream_t stream) {
    const float* x   = (const float*)d_in[0];
    const float* phi = (const float*)d_in[1];
    float*       out = (float*)d_out;

    const int B = in_sizes[0] / (L_BANDS * MN);   // 32

    dim3 grid(B * (M_DIM / 2));  // one block per (b, m-pair): 4096 blocks
    dim3 block(320);             // 2 rows x 155 active pair-threads
    cassi_fwd_kernel<<<grid, block, 0, stream>>>(x, phi, out);
}

// Round 6
// 83.030 us; speedup vs baseline: 1.4626x; 1.3131x over previous
//
#include <hip/hip_runtime.h>

// CASSI forward A^T(A(x)) — R5: two-dispatch stream separation.
//
// out[b,l,m,n] = phi[l,m,n] * y2[b,m,n+2l]
// y2[b,m,c]    = sum_l phi[l,m,c-2l] * x[b,l,m,c-2l]   (valid 0<=c-2l<N)
//
// History/evidence:
//  R2 (float2 gather + nt float2 stores, single kernel): 81 µs, mixed
//     read/write stream ~4.7 TB/s. nt stores keep out from evicting x in L3
//     (x+phi=242MB fits 256MB L3 across replays; R4 plain stores -> 109 µs).
//  fillBuffer on this chip: 7 TB/s PURE write stream.
// R5: kernel A = R2 phase 1 (proven all-56-loads-in-flight), writes y2
//     (10.5MB, plain store -> L3-resident). Kernel B = pure write stream:
//     y2 row staged in LDS (swizzled), phi float4 (L3-hit), aligned float4
//     nt stores. Separating streams lets each run at its own ceiling.

constexpr int L_BANDS = 28;
constexpr int M_DIM   = 256;
constexpr int N_DIM   = 256;
constexpr int SHIFT   = 2;
constexpr int N_OUT   = N_DIM + SHIFT * (L_BANDS - 1);  // 310
constexpr int NPAIR   = N_OUT / 2;                      // 155
constexpr int MN      = M_DIM * N_DIM;                  // 65536
constexpr int Y2S     = 320;                            // padded y2 row stride
constexpr int Y2PAD   = 352;                            // swz(309)=347 max

typedef float v2f __attribute__((ext_vector_type(2)));
typedef float v4f __attribute__((ext_vector_type(4)));

// LDS bank-deconflict skew (stride-4 read pattern in kernel B).
__device__ __forceinline__ int swz(int w) { return w + (w >> 3); }

// ---------------- Kernel A: gather x*phi -> y2 (read stream) ----------------
__global__ __launch_bounds__(320) void cassi_gather_kernel(
    const float* __restrict__ x,
    const float* __restrict__ phi,
    float* __restrict__ y2)
{
    const int t = threadIdx.x;
    const int r = (t >= 160) ? 1 : 0;
    const int p = t - 160 * r;
    if (p >= NPAIR) return;

    const int b  = blockIdx.x >> 7;
    const int m  = ((blockIdx.x & 127) << 1) + r;
    const int c0 = p << 1;

    const float* xb = x   + b * (L_BANDS * MN) + m * N_DIM;
    const float* pb = phi +                      m * N_DIM;

    v2f xr[L_BANDS];
    v2f pr[L_BANDS];
    #pragma unroll
    for (int l = 0; l < L_BANDS; ++l) {
        const int n0 = c0 - SHIFT * l;
        const bool v = (unsigned)n0 < (unsigned)(N_DIM - 1);
        if (v) {
            xr[l] = *(const v2f*)(xb + l * MN + n0);
            pr[l] = *(const v2f*)(pb + l * MN + n0);
        } else {
            xr[l] = (v2f)(0.0f);
            pr[l] = (v2f)(0.0f);
        }
    }
    v2f acc = (v2f)(0.0f);
    #pragma unroll
    for (int l = 0; l < L_BANDS; ++l) {
        acc += xr[l] * pr[l];
    }
    // plain store: y2 (10.5MB) should stay cached for kernel B.
    *(v2f*)(y2 + (b * M_DIM + m) * Y2S + c0) = acc;
}

// -------------- Kernel B: out = phi * gather(y2) (write stream) -------------
__global__ __launch_bounds__(256) void cassi_scatter_kernel(
    const float* __restrict__ phi,
    const float* __restrict__ y2,
    float* __restrict__ out)
{
    __shared__ float y2s[Y2PAD];

    const int t  = threadIdx.x;
    const int b  = blockIdx.x >> 8;
    const int m  = blockIdx.x & (M_DIM - 1);

    // Stage the 310-float y2 row into swizzled LDS.
    if (t < NPAIR) {
        const v2f v = *(const v2f*)(y2 + (b * M_DIM + m) * Y2S + (t << 1));
        y2s[swz(t << 1)]     = v.x;
        y2s[swz((t << 1) + 1)] = v.y;
    }
    __syncthreads();

    float* ob = out + b * (L_BANDS * MN) + m * N_DIM;

    // 7 passes x (4 bands per pass, 64 lanes x float4 per band).
    const int g  = t >> 6;      // 0..3: band-within-pass (whole wave same g)
    const int q  = t & 63;      // n-quad
    const int n0 = q << 2;
    #pragma unroll
    for (int pass = 0; pass < 7; ++pass) {
        const int l = (pass << 2) + g;
        const int w = n0 + SHIFT * l;
        const v4f p4 = *(const v4f*)(phi + l * MN + m * N_DIM + n0);
        v4f y4;
        y4.x = y2s[swz(w)];
        y4.y = y2s[swz(w + 1)];
        y4.z = y2s[swz(w + 2)];
        y4.w = y2s[swz(w + 3)];
        __builtin_nontemporal_store(p4 * y4, (v4f*)(ob + l * MN + n0));
    }
}

// ------------- Fallback: R2 single-kernel (if ws too small) -----------------
__global__ __launch_bounds__(320) void cassi_fused_kernel(
    const float* __restrict__ x,
    const float* __restrict__ phi,
    float* __restrict__ out)
{
    const int t = threadIdx.x;
    const int r = (t >= 160) ? 1 : 0;
    const int p = t - 160 * r;
    if (p >= NPAIR) return;

    const int b  = blockIdx.x >> 7;
    const int m  = ((blockIdx.x & 127) << 1) + r;
    const int c0 = p << 1;

    const float* xb = x   + b * (L_BANDS * MN) + m * N_DIM;
    const float* pb = phi +                      m * N_DIM;
    float*       ob = out + b * (L_BANDS * MN) + m * N_DIM;

    v2f xr[L_BANDS];
    v2f pr[L_BANDS];
    #pragma unroll
    for (int l = 0; l < L_BANDS; ++l) {
        const int n0 = c0 - SHIFT * l;
        const bool v = (unsigned)n0 < (unsigned)(N_DIM - 1);
        if (v) {
            xr[l] = *(const v2f*)(xb + l * MN + n0);
            pr[l] = *(const v2f*)(pb + l * MN + n0);
        } else {
            xr[l] = (v2f)(0.0f);
            pr[l] = (v2f)(0.0f);
        }
    }
    v2f acc = (v2f)(0.0f);
    #pragma unroll
    for (int l = 0; l < L_BANDS; ++l) {
        acc += xr[l] * pr[l];
    }
    #pragma unroll
    for (int l = 0; l < L_BANDS; ++l) {
        const int n0 = c0 - SHIFT * l;
        if ((unsigned)n0 < (unsigned)(N_DIM - 1)) {
            __builtin_nontemporal_store(pr[l] * acc, (v2f*)(ob + l * MN + n0));
        }
    }
}

extern "C" void kernel_launch(void* const* d_in, const int* in_sizes, int n_in,
                              void* d_out, int out_size, void* d_ws, size_t ws_size,
                              hipStream_t stream) {
    const float* x   = (const float*)d_in[0];
    const float* phi = (const float*)d_in[1];
    float*       out = (float*)d_out;

    const int B = in_sizes[0] / (L_BANDS * MN);   // 32

    const size_t y2_bytes = (size_t)B * M_DIM * Y2S * sizeof(float);  // 10.5 MB
    if (ws_size >= y2_bytes) {
        float* y2 = (float*)d_ws;
        cassi_gather_kernel<<<dim3(B * (M_DIM / 2)), dim3(320), 0, stream>>>(x, phi, y2);
        cassi_scatter_kernel<<<dim3(B * M_DIM), dim3(256), 0, stream>>>(phi, y2, out);
    } else {
        cassi_fused_kernel<<<dim3(B * (M_DIM / 2)), dim3(320), 0, stream>>>(x, phi, out);
    }
}